// Round 1
// baseline (1279.454 us; speedup 1.0000x reference)
//
#include <hip/hip_runtime.h>
#include <math.h>

#define Vv 50000
#define ED 300
#define POSD 4
#define DEPD 5
#define DIRD 1
#define IN_DIM 310
#define Hh 60
#define G4 240
#define NRELc 5
#define Bc 1024
#define Pc 16
#define Lc 8
#define Nc (Bc*Pc)
#define TN 8

__device__ __forceinline__ float sigf(float x){ return 1.f/(1.f+__expf(-x)); }

__global__ void zero_kernel(float* p, int n){
    int i = blockIdx.x*blockDim.x+threadIdx.x;
    int stride = gridDim.x*blockDim.x;
    for (; i<n; i+=stride) p[i]=0.f;
}

// Transpose weights to (d, 240) layout for coalesced per-gate-thread loads; fold biases.
__global__ void prep_kernel(const float* __restrict__ Wih0, const float* __restrict__ Whh0,
                            const float* __restrict__ Wih1, const float* __restrict__ Whh1,
                            const float* __restrict__ bih0, const float* __restrict__ bhh0,
                            const float* __restrict__ bih1, const float* __restrict__ bhh1,
                            float* __restrict__ Wih0T, float* __restrict__ Whh0T,
                            float* __restrict__ Wih1T, float* __restrict__ Whh1T,
                            float* __restrict__ bias0, float* __restrict__ bias1){
    int i = blockIdx.x*blockDim.x+threadIdx.x;
    int stride = gridDim.x*blockDim.x;
    for (int idx=i; idx<IN_DIM*G4; idx+=stride){ int d=idx/G4, j=idx-d*G4; Wih0T[idx]=Wih0[j*IN_DIM+d]; }
    for (int idx=i; idx<Hh*G4; idx+=stride){
        int k=idx/G4, j=idx-k*G4;
        Whh0T[idx]=Whh0[j*Hh+k];
        Wih1T[idx]=Wih1[j*Hh+k];
        Whh1T[idx]=Whh1[j*Hh+k];
    }
    if (i<G4){ bias0[i]=bih0[i]+bhh0[i]; bias1[i]=bih1[i]+bhh1[i]; }
}

// Layer-0 LSTM step: gather feats -> LDS, 240 gate threads x TN sequences.
__global__ __launch_bounds__(256) void step0_kernel(
    const int* __restrict__ widx, const int* __restrict__ pidx,
    const int* __restrict__ didx, const int* __restrict__ ridx,
    const float* __restrict__ wemb, const float* __restrict__ pemb,
    const float* __restrict__ demb, const float* __restrict__ remb,
    const float* __restrict__ WihT, const float* __restrict__ WhhT,
    const float* __restrict__ bias,
    float* __restrict__ h0, float* __restrict__ c0, float* __restrict__ h1t, int t)
{
    __shared__ float feat[TN][IN_DIM+2];
    __shared__ float hls[TN][Hh];
    __shared__ float gl[TN][G4];
    const int n0 = blockIdx.x*TN;
    const int tid = threadIdx.x;

    for (int idx=tid; idx<TN*ED; idx+=256){
        int nn=idx/ED, d=idx-nn*ED;
        int w = widx[(n0+nn)*Lc + t];
        feat[nn][d] = wemb[w*ED + d];
    }
    for (int idx=tid; idx<TN*(POSD+DEPD+DIRD); idx+=256){
        int nn=idx/(POSD+DEPD+DIRD), d=idx-nn*(POSD+DEPD+DIRD);
        int n=n0+nn;
        float v;
        if (d<POSD)            v = pemb[pidx[n*Lc+t]*POSD + d];
        else if (d<POSD+DEPD)  v = demb[didx[n*Lc+t]*DEPD + (d-POSD)];
        else                   v = remb[ridx[n*Lc+t]*DIRD];
        feat[nn][ED+d] = v;
    }
    for (int idx=tid; idx<TN*Hh; idx+=256){
        int nn=idx/Hh, k=idx-nn*Hh;
        hls[nn][k] = h0[(n0+nn)*Hh + k];
    }
    __syncthreads();

    if (tid < G4){
        float acc[TN];
#pragma unroll
        for (int nn=0;nn<TN;nn++) acc[nn]=0.f;
        for (int d=0; d<IN_DIM; d++){
            float w = WihT[d*G4 + tid];
#pragma unroll
            for (int nn=0;nn<TN;nn++) acc[nn] += feat[nn][d]*w;
        }
        for (int k=0;k<Hh;k++){
            float w = WhhT[k*G4 + tid];
#pragma unroll
            for (int nn=0;nn<TN;nn++) acc[nn] += hls[nn][k]*w;
        }
        float bb = bias[tid];
#pragma unroll
        for (int nn=0;nn<TN;nn++) gl[nn][tid] = acc[nn]+bb;
    }
    __syncthreads();

    for (int idx=tid; idx<TN*Hh; idx+=256){
        int nn=idx/Hh, k=idx-nn*Hh; int n=n0+nn;
        float ig = sigf(gl[nn][k]);
        float fg = sigf(gl[nn][Hh+k]);
        float gg = tanhf(gl[nn][2*Hh+k]);
        float og = sigf(gl[nn][3*Hh+k]);
        float c = fg*c0[n*Hh+k] + ig*gg;
        float h = og*tanhf(c);
        c0[n*Hh+k]=c; h0[n*Hh+k]=h; h1t[n*Hh+k]=h;
    }
}

// Layer-1 LSTM step; also captures h at t == len-1 into `last`.
__global__ __launch_bounds__(256) void step1_kernel(
    const float* __restrict__ xin,
    const float* __restrict__ WihT, const float* __restrict__ WhhT,
    const float* __restrict__ bias,
    float* __restrict__ h2, float* __restrict__ c2,
    const int* __restrict__ lens, float* __restrict__ last, int t)
{
    __shared__ float xls[TN][Hh];
    __shared__ float hls[TN][Hh];
    __shared__ float gl[TN][G4];
    const int n0 = blockIdx.x*TN;
    const int tid = threadIdx.x;

    for (int idx=tid; idx<TN*Hh; idx+=256){
        int nn=idx/Hh, k=idx-nn*Hh;
        xls[nn][k] = xin[(n0+nn)*Hh + k];
        hls[nn][k] = h2[(n0+nn)*Hh + k];
    }
    __syncthreads();

    if (tid < G4){
        float acc[TN];
#pragma unroll
        for (int nn=0;nn<TN;nn++) acc[nn]=0.f;
        for (int k=0;k<Hh;k++){
            float wi = WihT[k*G4+tid];
            float wh = WhhT[k*G4+tid];
#pragma unroll
            for (int nn=0;nn<TN;nn++) acc[nn] += xls[nn][k]*wi + hls[nn][k]*wh;
        }
        float bb=bias[tid];
#pragma unroll
        for (int nn=0;nn<TN;nn++) gl[nn][tid]=acc[nn]+bb;
    }
    __syncthreads();

    for (int idx=tid; idx<TN*Hh; idx+=256){
        int nn=idx/Hh, k=idx-nn*Hh; int n=n0+nn;
        float ig=sigf(gl[nn][k]);
        float fg=sigf(gl[nn][Hh+k]);
        float gg=tanhf(gl[nn][2*Hh+k]);
        float og=sigf(gl[nn][3*Hh+k]);
        float c = fg*c2[n*Hh+k] + ig*gg;
        float h = og*tanhf(c);
        c2[n*Hh+k]=c; h2[n*Hh+k]=h;
        if (t == lens[n]-1) last[n*Hh+k]=h;
    }
}

// Mean over P, concat [xw, path, yw] @ W^T + b, softmax. One block per batch row.
__global__ __launch_bounds__(320) void final_kernel(
    const float* __restrict__ last, const float* __restrict__ counts,
    const int* __restrict__ pair, const float* __restrict__ wemb,
    const float* __restrict__ W, const float* __restrict__ bvec,
    float* __restrict__ out)
{
    __shared__ float path[Hh];
    __shared__ float red[NRELc];
    const int b = blockIdx.x;
    const int tid = threadIdx.x;

    if (tid < Hh){
        float s=0.f, cs=0.f;
        for (int p=0;p<Pc;p++){
            float cnt = counts[b*Pc+p];
            s  += last[(b*Pc+p)*Hh + tid]*cnt;
            cs += cnt;
        }
        path[tid] = s/cs;
    }
    __syncthreads();

    const int r = tid>>6;      // wave id 0..4, one logit per wave
    const int lane = tid&63;
    const int xi = pair[b*2+0], yi = pair[b*2+1];
    const float* Wr = W + r*(2*ED+Hh);
    float acc=0.f;
    for (int d=lane; d<ED; d+=64) acc += wemb[xi*ED+d]*Wr[d];
    for (int k=lane; k<Hh; k+=64) acc += path[k]*Wr[ED+k];
    for (int d=lane; d<ED; d+=64) acc += wemb[yi*ED+d]*Wr[ED+Hh+d];
    for (int off=32; off>0; off>>=1) acc += __shfl_down(acc, off);
    if (lane==0) red[r] = acc + bvec[r];
    __syncthreads();

    if (tid==0){
        float m=red[0];
        for (int i=1;i<NRELc;i++) m=fmaxf(m,red[i]);
        float e[NRELc]; float s=0.f;
        for (int i=0;i<NRELc;i++){ e[i]=__expf(red[i]-m); s+=e[i]; }
        float inv=1.f/s;
        for (int i=0;i<NRELc;i++) out[b*NRELc+i]=e[i]*inv;
    }
}

extern "C" void kernel_launch(void* const* d_in, const int* in_sizes, int n_in,
                              void* d_out, int out_size, void* d_ws, size_t ws_size,
                              hipStream_t stream)
{
    const int*   word_idx = (const int*)d_in[0];
    const int*   pos_idx  = (const int*)d_in[1];
    const int*   dep_idx  = (const int*)d_in[2];
    const int*   dir_idx  = (const int*)d_in[3];
    const int*   lengths  = (const int*)d_in[4];
    const float* counts   = (const float*)d_in[5];
    const int*   pair_idx = (const int*)d_in[6];
    const float* word_emb = (const float*)d_in[7];
    const float* pos_emb  = (const float*)d_in[8];
    const float* dep_emb  = (const float*)d_in[9];
    const float* dir_emb  = (const float*)d_in[10];
    const float* Wih0     = (const float*)d_in[11];
    const float* Whh0     = (const float*)d_in[12];
    const float* bih0     = (const float*)d_in[13];
    const float* bhh0     = (const float*)d_in[14];
    const float* Wih1     = (const float*)d_in[15];
    const float* Whh1     = (const float*)d_in[16];
    const float* bih1     = (const float*)d_in[17];
    const float* bhh1     = (const float*)d_in[18];
    const float* W        = (const float*)d_in[19];
    const float* bvec     = (const float*)d_in[20];
    float* out = (float*)d_out;

    float* p = (float*)d_ws;
    float* Wih0T = p; p += IN_DIM*G4;
    float* Whh0T = p; p += Hh*G4;
    float* Wih1T = p; p += Hh*G4;
    float* Whh1T = p; p += Hh*G4;
    float* bias0 = p; p += G4;
    float* bias1 = p; p += G4;
    float* h0    = p; p += Nc*Hh;   // layer0 h   (zeroed; h0..c2 contiguous)
    float* c0    = p; p += Nc*Hh;   // layer0 c
    float* h2    = p; p += Nc*Hh;   // layer1 h
    float* c2    = p; p += Nc*Hh;   // layer1 c
    float* h1t   = p; p += Nc*Hh;   // layer0 output at current step
    float* lastb = p; p += Nc*Hh;   // h2 at t=len-1

    zero_kernel<<<512,256,0,stream>>>(h0, 4*Nc*Hh);
    prep_kernel<<<128,256,0,stream>>>(Wih0,Whh0,Wih1,Whh1,bih0,bhh0,bih1,bhh1,
                                      Wih0T,Whh0T,Wih1T,Whh1T,bias0,bias1);
    for (int t=0;t<Lc;t++){
        step0_kernel<<<Nc/TN,256,0,stream>>>(word_idx,pos_idx,dep_idx,dir_idx,
                                             word_emb,pos_emb,dep_emb,dir_emb,
                                             Wih0T,Whh0T,bias0,h0,c0,h1t,t);
        step1_kernel<<<Nc/TN,256,0,stream>>>(h1t,Wih1T,Whh1T,bias1,h2,c2,lengths,lastb,t);
    }
    final_kernel<<<Bc,320,0,stream>>>(lastb,counts,pair_idx,word_emb,W,bvec,out);
}

// Round 2
// 750.707 us; speedup vs baseline: 1.7043x; 1.7043x over previous
//
#include <hip/hip_runtime.h>
#include <hip/hip_bf16.h>
#include <math.h>

#define ED 300
#define IN_DIM 310
#define Hh 60
#define G4 240
#define NRELc 5
#define Bc 1024
#define Pc 16
#define Lc 8
#define Nc (Bc*Pc)        /* 16384 sequences */
#define Rc (Nc*Lc)        /* 131072 rows (t-major: r = t*Nc + n) */

typedef __hip_bfloat16 bf16;

__device__ __forceinline__ float sigf(float x){ return 1.f/(1.f+__expf(-x)); }
__device__ __forceinline__ float tanhfast(float x){
    x = fminf(fmaxf(x,-15.f),15.f);          // avoid inf/inf NaN
    float e = __expf(-2.f*x);
    return (1.f-e)/(1.f+e);
}

// Transpose weights to (k, 240) for contiguous wave-uniform s_load streams; fold biases.
__global__ void prep_kernel(const float* __restrict__ Wih0, const float* __restrict__ Whh0,
                            const float* __restrict__ Wih1, const float* __restrict__ Whh1,
                            const float* __restrict__ bih0, const float* __restrict__ bhh0,
                            const float* __restrict__ bih1, const float* __restrict__ bhh1,
                            float* __restrict__ Wih0T, float* __restrict__ Whh0T,
                            float* __restrict__ Wih1T, float* __restrict__ Whh1T,
                            float* __restrict__ bias0, float* __restrict__ bias1){
    int i = blockIdx.x*blockDim.x+threadIdx.x;
    int stride = gridDim.x*blockDim.x;
    for (int idx=i; idx<IN_DIM*G4; idx+=stride){ int d=idx/G4, j=idx-d*G4; Wih0T[idx]=Wih0[j*IN_DIM+d]; }
    for (int idx=i; idx<Hh*G4; idx+=stride){
        int k=idx/G4, j=idx-k*G4;
        Whh0T[idx]=Whh0[j*Hh+k];
        Wih1T[idx]=Wih1[j*Hh+k];
        Whh1T[idx]=Whh1[j*Hh+k];
    }
    if (i<G4){ bias0[i]=bih0[i]+bhh0[i]; bias1[i]=bih1[i]+bhh1[i]; }
}

// gin0[j][r] = bias0[j] + sum_k Wih0[j][k]*feat[r][k]   (fully parallel input GEMM)
// Thread = one row r, acc[120] in regs, weights via wave-uniform s_load. Two j-halves
// split across blockIdx parity.
__global__ __launch_bounds__(256) void gin0_kernel(
    const int* __restrict__ widx, const int* __restrict__ pidx,
    const int* __restrict__ didx, const int* __restrict__ ridx,
    const float* __restrict__ wemb, const float* __restrict__ pemb,
    const float* __restrict__ demb, const float* __restrict__ remb,
    const float* __restrict__ WihT, const float* __restrict__ bias0,
    bf16* __restrict__ gin0)
{
    const int jb = (blockIdx.x & 1) * 120;
    const int r  = (blockIdx.x >> 1) * 256 + threadIdx.x;
    const int t = r >> 14, n = r & (Nc-1);
    const int w = widx[n*Lc + t];
    const float4* wrow = (const float4*)(wemb + w*ED);

    float acc[120];
#pragma unroll
    for (int j=0;j<120;j++) acc[j] = bias0[jb+j];

    float4 cur = wrow[0];
    for (int k4=0;k4<75;k4++){
        float4 nxt = (k4<74) ? wrow[k4+1] : cur;   // prefetch next gather chunk
        {
            const float* wk = WihT + (k4*4+0)*G4 + jb; const float f = cur.x;
#pragma unroll
            for (int j=0;j<120;j++) acc[j] += wk[j]*f;
        }
        {
            const float* wk = WihT + (k4*4+1)*G4 + jb; const float f = cur.y;
#pragma unroll
            for (int j=0;j<120;j++) acc[j] += wk[j]*f;
        }
        {
            const float* wk = WihT + (k4*4+2)*G4 + jb; const float f = cur.z;
#pragma unroll
            for (int j=0;j<120;j++) acc[j] += wk[j]*f;
        }
        {
            const float* wk = WihT + (k4*4+3)*G4 + jb; const float f = cur.w;
#pragma unroll
            for (int j=0;j<120;j++) acc[j] += wk[j]*f;
        }
        cur = nxt;
    }
    // tail feature rows 300..309 (pos/dep/dir); d-loop runtime so j-body appears once
    const int pp = pidx[n*Lc+t], dd = didx[n*Lc+t], rr = ridx[n*Lc+t];
    for (int d=0; d<10; d++){
        float f;
        if (d<4)       f = pemb[pp*4+d];
        else if (d<9)  f = demb[dd*5+(d-4)];
        else           f = remb[rr];
        const float* wk = WihT + (300+d)*G4 + jb;
#pragma unroll
        for (int j=0;j<120;j++) acc[j] += wk[j]*f;
    }
#pragma unroll
    for (int j=0;j<120;j++) gin0[(jb+j)*Rc + r] = __float2bfloat16(acc[j]);
}

// Layer-0 recurrence. Block = 64 sequences, 4 waves; wave g owns gate-type g
// (weights wave-uniform -> s_load). h in LDS (per-lane b128 reads: 15 per 3600 FMA).
__global__ __launch_bounds__(256) void rec0_kernel(
    const bf16* __restrict__ gin0, const float* __restrict__ WhhT,
    bf16* __restrict__ h1T)
{
    __shared__ float hlds[64][60];
    __shared__ float gact[4][60][64];
    const int tid = threadIdx.x;
    const int l = tid & 63;
    const int g = __builtin_amdgcn_readfirstlane(tid >> 6);  // prove wave-uniform
    const int n0 = blockIdx.x * 64;
    const int n = n0 + l;

    for (int idx=tid; idx<64*60; idx+=256) ((float*)hlds)[idx] = 0.f;
    float c_reg[15];
#pragma unroll
    for (int i=0;i<15;i++) c_reg[i]=0.f;
    __syncthreads();

    for (int t=0;t<Lc;t++){
        // P1: acc[u] = gin0 + Whh h
        float acc[60];
        const bf16* gbase = gin0 + (g*60)*Rc + t*Nc + n;
#pragma unroll
        for (int u=0;u<60;u++) acc[u] = __bfloat162float(gbase[u*Rc]);
        const float* wbase = WhhT + g*60;
        for (int k4=0;k4<15;k4++){
            const float4 hf = *(const float4*)&hlds[l][k4*4];
            {
                const float* wk = wbase + (k4*4+0)*G4; const float h = hf.x;
#pragma unroll
                for (int u=0;u<60;u++) acc[u] += wk[u]*h;
            }
            {
                const float* wk = wbase + (k4*4+1)*G4; const float h = hf.y;
#pragma unroll
                for (int u=0;u<60;u++) acc[u] += wk[u]*h;
            }
            {
                const float* wk = wbase + (k4*4+2)*G4; const float h = hf.z;
#pragma unroll
                for (int u=0;u<60;u++) acc[u] += wk[u]*h;
            }
            {
                const float* wk = wbase + (k4*4+3)*G4; const float h = hf.w;
#pragma unroll
                for (int u=0;u<60;u++) acc[u] += wk[u]*h;
            }
        }
        // P2: activation, publish gates
        if (g==2){
#pragma unroll
            for (int u=0;u<60;u++) gact[2][u][l] = tanhfast(acc[u]);
        } else {
#pragma unroll
            for (int u=0;u<60;u++) gact[g][u][l] = sigf(acc[u]);
        }
        __syncthreads();
        // P3: c/h update; thread handles (n=l, u = waveid+4i), c statically indexed
#pragma unroll
        for (int i=0;i<15;i++){
            const int u = (tid>>6) + 4*i;
            float iv = gact[0][u][l], fv = gact[1][u][l];
            float gv = gact[2][u][l], ov = gact[3][u][l];
            float c = fv*c_reg[i] + iv*gv;
            c_reg[i] = c;
            float h = ov*tanhfast(c);
            hlds[l][u] = h;
            h1T[u*Rc + t*Nc + n] = __float2bfloat16(h);
        }
        __syncthreads();
    }
}

// gin1[j][r] = bias1[j] + sum_k Wih1[j][k]*h1[r][k]  (parallel; x in 1 rolling reg)
__global__ __launch_bounds__(256) void gin1_kernel(
    const bf16* __restrict__ h1T, const float* __restrict__ WihT,
    const float* __restrict__ bias1, bf16* __restrict__ gin1)
{
    const int jb = (blockIdx.x & 1)*120;
    const int r = (blockIdx.x>>1)*256 + threadIdx.x;
    float acc[120];
#pragma unroll
    for (int j=0;j<120;j++) acc[j] = bias1[jb+j];
    float f = __bfloat162float(h1T[r]);
    for (int k=0;k<Hh;k++){
        float fn = (k<Hh-1) ? __bfloat162float(h1T[(k+1)*Rc + r]) : 0.f;
        const float* wk = WihT + k*G4 + jb;
#pragma unroll
        for (int j=0;j<120;j++) acc[j] += wk[j]*f;
        f = fn;
    }
#pragma unroll
    for (int j=0;j<120;j++) gin1[(jb+j)*Rc + r] = __float2bfloat16(acc[j]);
}

// Layer-1 recurrence; captures h2 at t == len-1 into lastT[u][n] (coalesced).
__global__ __launch_bounds__(256) void rec1_kernel(
    const bf16* __restrict__ gin1, const float* __restrict__ WhhT,
    const int* __restrict__ lens, float* __restrict__ lastT)
{
    __shared__ float hlds[64][60];
    __shared__ float gact[4][60][64];
    const int tid = threadIdx.x;
    const int l = tid & 63;
    const int g = __builtin_amdgcn_readfirstlane(tid >> 6);
    const int n0 = blockIdx.x * 64;
    const int n = n0 + l;
    const int mylen = lens[n];

    for (int idx=tid; idx<64*60; idx+=256) ((float*)hlds)[idx] = 0.f;
    float c_reg[15];
#pragma unroll
    for (int i=0;i<15;i++) c_reg[i]=0.f;
    __syncthreads();

    for (int t=0;t<Lc;t++){
        float acc[60];
        const bf16* gbase = gin1 + (g*60)*Rc + t*Nc + n;
#pragma unroll
        for (int u=0;u<60;u++) acc[u] = __bfloat162float(gbase[u*Rc]);
        const float* wbase = WhhT + g*60;
        for (int k4=0;k4<15;k4++){
            const float4 hf = *(const float4*)&hlds[l][k4*4];
            {
                const float* wk = wbase + (k4*4+0)*G4; const float h = hf.x;
#pragma unroll
                for (int u=0;u<60;u++) acc[u] += wk[u]*h;
            }
            {
                const float* wk = wbase + (k4*4+1)*G4; const float h = hf.y;
#pragma unroll
                for (int u=0;u<60;u++) acc[u] += wk[u]*h;
            }
            {
                const float* wk = wbase + (k4*4+2)*G4; const float h = hf.z;
#pragma unroll
                for (int u=0;u<60;u++) acc[u] += wk[u]*h;
            }
            {
                const float* wk = wbase + (k4*4+3)*G4; const float h = hf.w;
#pragma unroll
                for (int u=0;u<60;u++) acc[u] += wk[u]*h;
            }
        }
        if (g==2){
#pragma unroll
            for (int u=0;u<60;u++) gact[2][u][l] = tanhfast(acc[u]);
        } else {
#pragma unroll
            for (int u=0;u<60;u++) gact[g][u][l] = sigf(acc[u]);
        }
        __syncthreads();
#pragma unroll
        for (int i=0;i<15;i++){
            const int u = (tid>>6) + 4*i;
            float iv = gact[0][u][l], fv = gact[1][u][l];
            float gv = gact[2][u][l], ov = gact[3][u][l];
            float c = fv*c_reg[i] + iv*gv;
            c_reg[i] = c;
            float h = ov*tanhfast(c);
            hlds[l][u] = h;
            if (t == mylen-1) lastT[u*Nc + n] = h;
        }
        __syncthreads();
    }
}

// Mean over P, concat [xw, path, yw] @ W^T + b, softmax. One block per batch row.
__global__ __launch_bounds__(320) void final_kernel(
    const float* __restrict__ lastT, const float* __restrict__ counts,
    const int* __restrict__ pair, const float* __restrict__ wemb,
    const float* __restrict__ W, const float* __restrict__ bvec,
    float* __restrict__ out)
{
    __shared__ float path[Hh];
    __shared__ float red[NRELc];
    const int b = blockIdx.x;
    const int tid = threadIdx.x;

    if (tid < Hh){
        float s=0.f, cs=0.f;
        for (int p=0;p<Pc;p++){
            float cnt = counts[b*Pc+p];
            s  += lastT[tid*Nc + b*Pc+p]*cnt;
            cs += cnt;
        }
        path[tid] = s/cs;
    }
    __syncthreads();

    const int rrel = tid>>6;      // wave id 0..4, one logit per wave
    const int lane = tid&63;
    const int xi = pair[b*2+0], yi = pair[b*2+1];
    const float* Wr = W + rrel*(2*ED+Hh);
    float acc=0.f;
    for (int d=lane; d<ED; d+=64) acc += wemb[xi*ED+d]*Wr[d];
    for (int k=lane; k<Hh; k+=64) acc += path[k]*Wr[ED+k];
    for (int d=lane; d<ED; d+=64) acc += wemb[yi*ED+d]*Wr[ED+Hh+d];
    for (int off=32; off>0; off>>=1) acc += __shfl_down(acc, off);
    if (lane==0) red[rrel] = acc + bvec[rrel];
    __syncthreads();

    if (tid==0){
        float m=red[0];
        for (int i=1;i<NRELc;i++) m=fmaxf(m,red[i]);
        float e[NRELc]; float s=0.f;
        for (int i=0;i<NRELc;i++){ e[i]=__expf(red[i]-m); s+=e[i]; }
        float inv=1.f/s;
        for (int i=0;i<NRELc;i++) out[b*NRELc+i]=e[i]*inv;
    }
}

extern "C" void kernel_launch(void* const* d_in, const int* in_sizes, int n_in,
                              void* d_out, int out_size, void* d_ws, size_t ws_size,
                              hipStream_t stream)
{
    const int*   word_idx = (const int*)d_in[0];
    const int*   pos_idx  = (const int*)d_in[1];
    const int*   dep_idx  = (const int*)d_in[2];
    const int*   dir_idx  = (const int*)d_in[3];
    const int*   lengths  = (const int*)d_in[4];
    const float* counts   = (const float*)d_in[5];
    const int*   pair_idx = (const int*)d_in[6];
    const float* word_emb = (const float*)d_in[7];
    const float* pos_emb  = (const float*)d_in[8];
    const float* dep_emb  = (const float*)d_in[9];
    const float* dir_emb  = (const float*)d_in[10];
    const float* Wih0     = (const float*)d_in[11];
    const float* Whh0     = (const float*)d_in[12];
    const float* bih0     = (const float*)d_in[13];
    const float* bhh0     = (const float*)d_in[14];
    const float* Wih1     = (const float*)d_in[15];
    const float* Whh1     = (const float*)d_in[16];
    const float* bih1     = (const float*)d_in[17];
    const float* bhh1     = (const float*)d_in[18];
    const float* W        = (const float*)d_in[19];
    const float* bvec     = (const float*)d_in[20];
    float* out = (float*)d_out;

    // Workspace carve-up (~146 MB): fp32 region then bf16 region.
    float* p = (float*)d_ws;
    float* Wih0T = p; p += IN_DIM*G4;
    float* Whh0T = p; p += Hh*G4;
    float* Wih1T = p; p += Hh*G4;
    float* Whh1T = p; p += Hh*G4;
    float* bias0 = p; p += G4;
    float* bias1 = p; p += G4;
    float* lastT = p; p += Nc*Hh;
    bf16* q = (bf16*)p;
    bf16* gin0 = q; q += (size_t)G4*Rc;
    bf16* gin1 = q; q += (size_t)G4*Rc;
    bf16* h1T  = q; q += (size_t)Hh*Rc;

    prep_kernel<<<128,256,0,stream>>>(Wih0,Whh0,Wih1,Whh1,bih0,bhh0,bih1,bhh1,
                                      Wih0T,Whh0T,Wih1T,Whh1T,bias0,bias1);
    gin0_kernel<<<1024,256,0,stream>>>(word_idx,pos_idx,dep_idx,dir_idx,
                                       word_emb,pos_emb,dep_emb,dir_emb,
                                       Wih0T,bias0,gin0);
    rec0_kernel<<<Nc/64,256,0,stream>>>(gin0,Whh0T,h1T);
    gin1_kernel<<<1024,256,0,stream>>>(h1T,Wih1T,bias1,gin1);
    rec1_kernel<<<Nc/64,256,0,stream>>>(gin1,Whh1T,lengths,lastT);
    final_kernel<<<Bc,320,0,stream>>>(lastT,counts,pair_idx,word_emb,W,bvec,out);
}